// Round 9
// baseline (107.689 us; speedup 1.0000x reference)
//
#include <hip/hip_runtime.h>
#include <hip/hip_fp16.h>

#define B_ 4
#define H_ 128
#define W_ 128
#define HW_ 16384

typedef _Float16 half8 __attribute__((ext_vector_type(8)));
typedef float floatx4 __attribute__((ext_vector_type(4)));

// ws layout (bytes):
//   W2L : f16 [9 tap][2 ks][4 og][64 lane][8]  = 73,728   at offset 0
//   W0L : f16 [9 tap][2 ks][2 h][64 lane][8]   = 36,864   at offset 73,728

// ---------------- prep: weight swizzles only ----------------
__global__ __launch_bounds__(256) void k_prep_w(
    const float* __restrict__ w_dcn, const float* __restrict__ w_off,
    __half* __restrict__ W2L, __half* __restrict__ W0L)
{
    int idx = blockIdx.x*256 + threadIdx.x;     // exactly 55,296 threads
    if (idx < 36864) {
        int e = idx & 7, lane = (idx>>3) & 63, og = (idx>>9) & 3;
        int ks = (idx>>11) & 1, tap = idx >> 12;
        int o = og*16 + (lane & 15);
        int c = ks*32 + (lane >> 4)*8 + e;
        W2L[idx] = __float2half(w_dcn[o*576 + c*9 + tap]);
    } else {
        int i2 = idx - 36864;
        int e = i2 & 7, lane = (i2>>3) & 63, h = (i2>>9) & 1;
        int ks = (i2>>10) & 1, tap = i2 >> 11;
        int oc = h*16 + (lane & 15);
        int c = ks*32 + (lane >> 4)*8 + e;
        W0L[i2] = (oc < 18) ? __float2half(w_off[oc*576 + c*9 + tap])
                            : __float2half(0.f);
    }
}

// ---------------- fused kernel ----------------
// block = 256 thr = 4 waves, 64 positions as a 2-row x 32-col tile.
// Stages halo directly from f32 NCHW. lane (m,q) of wave w OWNS pos = w*16+m,
// channel chunks q / q+4 == its MFMA A-frag. Descriptors built INLINE per-lane
// (redundant across q — free in wave time); no desc LDS array, 2 fewer barriers.
// LDS = 32,512 B -> 5 blocks/CU (20 waves) with launch_bounds(256,5):
//   haloT: [8 chunk][216 pix(6r x 36c)] b128, chunk stride 3488 B
//   offL : [64 pos][18 f32] stride-18 (gcd(18,32)=2 -> conflict-free reads)
//   epilogue E[64][66] f32 aliases haloT after final barrier
#define CHS2 3488
#define OFFL_OFF 27904
#define SMEM_SZ 32512

__global__ __launch_bounds__(256, 5) void k_fused(
    const float* __restrict__ x, const _Float16* __restrict__ W2L,
    const _Float16* __restrict__ W0L, const float* __restrict__ b_off,
    const float* __restrict__ b_dcn, float* __restrict__ out)
{
    __shared__ __attribute__((aligned(16))) char smem[SMEM_SZ];
    char*  halo_c = smem;
    float* offL   = (float*)(smem + OFFL_OFF);

    int t = threadIdx.x;
    int lane = t & 63;
    int w = __builtin_amdgcn_readfirstlane(t >> 6);
    int m = lane & 15, q = lane >> 4;

    // XCD swizzle: contiguous half-image (one batch half) per XCD
    int bid  = blockIdx.x;
    int xcd  = bid & 7, sidx = bid >> 3;
    int orig = xcd*128 + sidx;
    int b    = orig >> 8;
    int rem  = orig & 255;
    int i0   = (rem >> 2) * 2;     // row-pair base
    int j0   = (rem & 3) * 32;     // col base

    const float* xf = x + (size_t)b * (64*HW_);

    // ---------- stage 6-row x 36-col halo from f32 NCHW, chunk-transposed ----------
    #pragma unroll
    for (int rep = 0; rep < 7; ++rep) {
        int idx = rep*256 + t;                  // 1728 tasks
        if (idx < 1728) {
            int ch = idx / 216, pl = idx - ch*216;
            int hr = pl / 36, hx = pl - hr*36;
            int grow = min(max(i0 - 2 + hr, 0), H_-1);
            int gcol = min(max(j0 - 2 + hx, 0), W_-1);
            int gpix = (grow<<7) + gcol;
            const float* s = xf + ch*8*HW_ + gpix;
            half8 v;
            #pragma unroll
            for (int e = 0; e < 8; ++e) v[e] = (_Float16)s[e*HW_];
            *(half8*)(halo_c + ch*CHS2 + pl*16) = v;
        }
    }
    __syncthreads();

    // ================= Phase A: offset conv from haloT =================
    floatx4 accA[2];
    #pragma unroll
    for (int h = 0; h < 2; ++h) accA[h] = (floatx4){0.f,0.f,0.f,0.f};

    const half8 hz = {0,0,0,0,0,0,0,0};
    int pcol = w*16 + m;
    int rA = pcol >> 5, cA = pcol & 31;
    #pragma unroll
    for (int tap = 0; tap < 9; ++tap) {
        int kh = tap/3, kw = tap - (tap/3)*3;
        int ii = i0 + rA - 1 + kh;
        int jj = j0 + cA - 1 + kw;
        bool valid = (ii >= 0) && (ii < H_) && (jj >= 0) && (jj < W_);
        int pixA = (rA + 1 + kh)*36 + (cA + 1 + kw);
        half8 a0 = *(const half8*)(halo_c + q*CHS2     + pixA*16);
        half8 a1 = *(const half8*)(halo_c + (q+4)*CHS2 + pixA*16);
        a0 = valid ? a0 : hz;
        a1 = valid ? a1 : hz;
        #pragma unroll
        for (int ks = 0; ks < 2; ++ks) {
            half8 a = ks ? a1 : a0;
            #pragma unroll
            for (int h = 0; h < 2; ++h) {
                half8 bf = *(const half8*)(W0L + (((tap*2+ks)*2+h)<<9) + (lane<<3));
                accA[h] = __builtin_amdgcn_mfma_f32_16x16x32_f16(a, bf, accA[h], 0, 0, 0);
            }
        }
    }
    // epilogue A: D col=m (=oc), row=q*4+r (=pos in wave tile); offL stride 18
    #pragma unroll
    for (int h = 0; h < 2; ++h) {
        int oc = h*16 + m;
        if (oc < 18) {
            float bo = b_off[oc];
            #pragma unroll
            for (int r = 0; r < 4; ++r)
                offL[(w*16 + q*4 + r)*18 + oc] = accA[h][r] + bo;
        }
    }
    __syncthreads();

    // ========== Phase B: inline desc + own-pos sample + MFMA, barrier-free ==========
    floatx4 acc[4];
    #pragma unroll
    for (int og = 0; og < 4; ++og) acc[og] = (floatx4){0.f,0.f,0.f,0.f};

    const char* hq0 = halo_c + q*CHS2;
    const char* hq1 = halo_c + (q+4)*CHS2;
    int mypos = w*16 + m;
    int rB = mypos >> 5, cB = mypos & 31;
    const float* offme = offL + mypos*18;

    for (int tap = 0; tap < 9; ++tap) {
        int kh = tap/3, kw = tap - (tap/3)*3;
        // ---- inline descriptor (same for all q lanes of this m — free) ----
        float2 o2 = *(const float2*)(offme + 2*tap);
        float py = (float)(i0 + rB - 1 + kh) + o2.x;
        float px = (float)(j0 + cB - 1 + kw) + o2.y;
        float y0f = floorf(py), x0f = floorf(px);
        float dy = py - y0f, dx = px - x0f;
        int y0 = (int)y0f, x0i = (int)x0f;
        int y1 = y0 + 1,  x1 = x0i + 1;
        bool vy0 = (y0>=0)&(y0<H_),   vy1 = (y1>=0)&(y1<H_);
        bool vx0 = (x0i>=0)&(x0i<W_), vx1 = (x1>=0)&(x1<W_);
        int yc0 = min(max(y0,0),H_-1),  yc1 = min(max(y1,0),H_-1);
        int xc0 = min(max(x0i,0),W_-1), xc1 = min(max(x1,0),W_-1);
        float w00f = (1.f-dy)*(1.f-dx) * ((vy0&&vx0)?1.f:0.f);
        float w01f = (1.f-dy)*dx       * ((vy0&&vx1)?1.f:0.f);
        float w10f = dy*(1.f-dx)       * ((vy1&&vx0)?1.f:0.f);
        float w11f = dy*dx             * ((vy1&&vx1)?1.f:0.f);
        int hy0 = yc0 - (i0-2), hy1 = yc1 - (i0-2);
        int hx0 = xc0 - (j0-2), hx1 = xc1 - (j0-2);
        bool inh = ((unsigned)hy0 < 6u) & ((unsigned)hy1 < 6u)
                 & ((unsigned)hx0 < 36u) & ((unsigned)hx1 < 36u);
        _Float16 h00 = (_Float16)w00f, h01 = (_Float16)w01f;
        _Float16 h10 = (_Float16)w10f, h11 = (_Float16)w11f;
        half8 W00 = {h00,h00,h00,h00,h00,h00,h00,h00};
        half8 W01 = {h01,h01,h01,h01,h01,h01,h01,h01};
        half8 W10 = {h10,h10,h10,h10,h10,h10,h10,h10};
        half8 W11 = {h11,h11,h11,h11,h11,h11,h11,h11};
        half8 v00a,v01a,v10a,v11a, v00b,v01b,v10b,v11b;
        if (inh) {
            int p00 = hy0*36+hx0, p01 = hy0*36+hx1;
            int p10 = hy1*36+hx0, p11 = hy1*36+hx1;
            v00a = *(const half8*)(hq0 + p00*16);  v00b = *(const half8*)(hq1 + p00*16);
            v01a = *(const half8*)(hq0 + p01*16);  v01b = *(const half8*)(hq1 + p01*16);
            v10a = *(const half8*)(hq0 + p10*16);  v10b = *(const half8*)(hq1 + p10*16);
            v11a = *(const half8*)(hq0 + p11*16);  v11b = *(const half8*)(hq1 + p11*16);
        } else {
            // rare out-of-halo: scalar f32 NCHW gathers (exec-masked)
            int g00 = (yc0<<7)+xc0, g01 = (yc0<<7)+xc1;
            int g10 = (yc1<<7)+xc0, g11 = (yc1<<7)+xc1;
            #pragma unroll
            for (int e = 0; e < 8; ++e) {
                v00a[e] = (_Float16)xf[(q*8+e)*HW_ + g00];
                v00b[e] = (_Float16)xf[((q+4)*8+e)*HW_ + g00];
                v01a[e] = (_Float16)xf[(q*8+e)*HW_ + g01];
                v01b[e] = (_Float16)xf[((q+4)*8+e)*HW_ + g01];
                v10a[e] = (_Float16)xf[(q*8+e)*HW_ + g10];
                v10b[e] = (_Float16)xf[((q+4)*8+e)*HW_ + g10];
                v11a[e] = (_Float16)xf[(q*8+e)*HW_ + g11];
                v11b[e] = (_Float16)xf[((q+4)*8+e)*HW_ + g11];
            }
        }
        half8 sk0 = v00a*W00 + v01a*W01 + v10a*W10 + v11a*W11;
        half8 sk1 = v00b*W00 + v01b*W01 + v10b*W10 + v11b*W11;
        #pragma unroll
        for (int og = 0; og < 4; ++og) {
            half8 bf0 = *(const half8*)(W2L + (((tap*2+0)*4+og)<<9) + (lane<<3));
            acc[og] = __builtin_amdgcn_mfma_f32_16x16x32_f16(sk0, bf0, acc[og], 0, 0, 0);
            half8 bf1 = *(const half8*)(W2L + (((tap*2+1)*4+og)<<9) + (lane<<3));
            acc[og] = __builtin_amdgcn_mfma_f32_16x16x32_f16(sk1, bf1, acc[og], 0, 0, 0);
        }
    }
    __syncthreads();   // halo+offL dead; epilogue E aliases halo

    // epilogue: D col=m -> o=og*16+m, row=q*4+r -> pos=w*16+q*4+r
    float* E = (float*)smem;   // [64 pos][66]
    #pragma unroll
    for (int og = 0; og < 4; ++og) {
        #pragma unroll
        for (int r = 0; r < 4; ++r)
            E[(w*16 + q*4 + r)*66 + og*16 + m] = acc[og][r];
    }
    __syncthreads();
    int obase = (b*64)*HW_ + i0*W_ + j0;
    int orow = (lane >> 5)*W_ + (lane & 31);
    #pragma unroll
    for (int rep = 0; rep < 16; ++rep) {
        int o = rep*4 + w;
        out[obase + o*HW_ + orow] = E[lane*66 + o] + b_dcn[o];
    }
}

extern "C" void kernel_launch(void* const* d_in, const int* in_sizes, int n_in,
                              void* d_out, int out_size, void* d_ws, size_t ws_size,
                              hipStream_t stream) {
    const float* x     = (const float*)d_in[0];
    const float* w_off = (const float*)d_in[1];
    const float* b_off = (const float*)d_in[2];
    const float* w_dcn = (const float*)d_in[3];
    const float* b_dcn = (const float*)d_in[4];
    float* out = (float*)d_out;

    __half* W2L = (__half*)d_ws;                    // 73,728 B
    __half* W0L = (__half*)((char*)d_ws + 73728);   // 36,864 B

    k_prep_w<<<216, 256, 0, stream>>>(w_dcn, w_off, W2L, W0L);
    k_fused<<<1024, 256, 0, stream>>>(x, (const _Float16*)W2L,
                                      (const _Float16*)W0L, b_off, b_dcn, out);
}

// Round 10
// 96.654 us; speedup vs baseline: 1.1142x; 1.1142x over previous
//
#include <hip/hip_runtime.h>
#include <hip/hip_fp16.h>

#define B_ 4
#define H_ 128
#define W_ 128
#define HW_ 16384

typedef _Float16 half8 __attribute__((ext_vector_type(8)));
typedef float floatx4 __attribute__((ext_vector_type(4)));

// ws layout (bytes):
//   W2L : f16 [9 tap][2 ks][4 og][64 lane][8]  = 73,728   at offset 0
//   W0L : f16 [9 tap][2 ks][2 h][64 lane][8]   = 36,864   at offset 73,728

// ---------------- prep: weight swizzles only ----------------
__global__ __launch_bounds__(256) void k_prep_w(
    const float* __restrict__ w_dcn, const float* __restrict__ w_off,
    __half* __restrict__ W2L, __half* __restrict__ W0L)
{
    int idx = blockIdx.x*256 + threadIdx.x;     // exactly 55,296 threads
    if (idx < 36864) {
        int e = idx & 7, lane = (idx>>3) & 63, og = (idx>>9) & 3;
        int ks = (idx>>11) & 1, tap = idx >> 12;
        int o = og*16 + (lane & 15);
        int c = ks*32 + (lane >> 4)*8 + e;
        W2L[idx] = __float2half(w_dcn[o*576 + c*9 + tap]);
    } else {
        int i2 = idx - 36864;
        int e = i2 & 7, lane = (i2>>3) & 63, h = (i2>>9) & 1;
        int ks = (i2>>10) & 1, tap = i2 >> 11;
        int oc = h*16 + (lane & 15);
        int c = ks*32 + (lane >> 4)*8 + e;
        W0L[i2] = (oc < 18) ? __float2half(w_off[oc*576 + c*9 + tap])
                            : __float2half(0.f);
    }
}

// ---------------- fused kernel ----------------
// block = 256 thr = 4 waves, 64 positions as a 2-row x 32-col tile.
// Stages halo from f32 NCHW. lane (m,q) of wave w OWNS pos = w*16+m,
// channel chunks q / q+4 == its MFMA A-frag.
// KEY: offL -> desc -> Phase-B is WAVE-LOCAL (wave w only ever touches its own
// 16 positions), so each wave gets a private 2,304 B offL/desc region and the
// post-epilogue-A + post-desc-store barriers vanish. 3 barriers total.
// LDS = 37,120 B -> 4 blocks/CU:
//   haloT : [8 chunk][216 pix(6r x 36c)] b128, chunk stride 3488 B
//   wavereg[w] (2,304 B each): offL[16 pos][18 f32] (1,152 B), then overwritten
//            in-wave (regs-staged, lockstep-safe) by desc[144][16 B]
//   epilogue E[64][66] f32 aliases haloT after final barrier
#define CHS2 3488
#define WLOC_OFF 27904
#define SMEM_SZ 37120

__global__ __launch_bounds__(256, 4) void k_fused(
    const float* __restrict__ x, const _Float16* __restrict__ W2L,
    const _Float16* __restrict__ W0L, const float* __restrict__ b_off,
    const float* __restrict__ b_dcn, float* __restrict__ out)
{
    __shared__ __attribute__((aligned(16))) char smem[SMEM_SZ];
    char* halo_c = smem;

    int t = threadIdx.x;
    int lane = t & 63;
    int w = __builtin_amdgcn_readfirstlane(t >> 6);
    int m = lane & 15, q = lane >> 4;

    char*  wl     = smem + WLOC_OFF + w*2304;   // this wave's private region
    float* offL   = (float*)wl;                 // [16 pos][18] f32
    char*  desc   = wl;                         // [144][16 B], overwrites offL

    // XCD swizzle: contiguous half-image (one batch half) per XCD
    int bid  = blockIdx.x;
    int xcd  = bid & 7, sidx = bid >> 3;
    int orig = xcd*128 + sidx;
    int b    = orig >> 8;
    int rem  = orig & 255;
    int i0   = (rem >> 2) * 2;     // row-pair base
    int j0   = (rem & 3) * 32;     // col base

    const float* xf = x + (size_t)b * (64*HW_);

    // ---------- stage 6-row x 36-col halo from f32 NCHW, chunk-transposed ----------
    #pragma unroll
    for (int rep = 0; rep < 7; ++rep) {
        int idx = rep*256 + t;                  // 1728 tasks
        if (idx < 1728) {
            int ch = idx / 216, pl = idx - ch*216;
            int hr = pl / 36, hx = pl - hr*36;
            int grow = min(max(i0 - 2 + hr, 0), H_-1);
            int gcol = min(max(j0 - 2 + hx, 0), W_-1);
            int gpix = (grow<<7) + gcol;
            const float* s = xf + ch*8*HW_ + gpix;
            half8 v;
            #pragma unroll
            for (int e = 0; e < 8; ++e) v[e] = (_Float16)s[e*HW_];
            *(half8*)(halo_c + ch*CHS2 + pl*16) = v;
        }
    }
    __syncthreads();   // barrier 1 of 3 (halo is cross-wave)

    // ================= Phase A: offset conv from haloT =================
    floatx4 accA[2];
    #pragma unroll
    for (int h = 0; h < 2; ++h) accA[h] = (floatx4){0.f,0.f,0.f,0.f};

    const half8 hz = {0,0,0,0,0,0,0,0};
    int pcol = w*16 + m;
    int rA = pcol >> 5, cA = pcol & 31;
    #pragma unroll
    for (int tap = 0; tap < 9; ++tap) {
        int kh = tap/3, kw = tap - (tap/3)*3;
        int ii = i0 + rA - 1 + kh;
        int jj = j0 + cA - 1 + kw;
        bool valid = (ii >= 0) && (ii < H_) && (jj >= 0) && (jj < W_);
        int pixA = (rA + 1 + kh)*36 + (cA + 1 + kw);
        half8 a0 = *(const half8*)(halo_c + q*CHS2     + pixA*16);
        half8 a1 = *(const half8*)(halo_c + (q+4)*CHS2 + pixA*16);
        a0 = valid ? a0 : hz;
        a1 = valid ? a1 : hz;
        #pragma unroll
        for (int ks = 0; ks < 2; ++ks) {
            half8 a = ks ? a1 : a0;
            #pragma unroll
            for (int h = 0; h < 2; ++h) {
                half8 bf = *(const half8*)(W0L + (((tap*2+ks)*2+h)<<9) + (lane<<3));
                accA[h] = __builtin_amdgcn_mfma_f32_16x16x32_f16(a, bf, accA[h], 0, 0, 0);
            }
        }
    }
    // epilogue A (wave-local): D col=m (=oc), row=q*4+r -> local pos q*4+r
    #pragma unroll
    for (int h = 0; h < 2; ++h) {
        int oc = h*16 + m;
        if (oc < 18) {
            float bo = b_off[oc];
            #pragma unroll
            for (int r = 0; r < 4; ++r)
                offL[(q*4 + r)*18 + oc] = accA[h][r] + bo;
        }
    }
    // NO barrier: same-wave DS ops are in-order; desc build below reads only
    // this wave's offL.

    // ======== descriptor build (wave-local): regs first, then store ========
    uint4 dreg[3];
    #pragma unroll
    for (int e = 0; e < 3; ++e) {
        int idx = e*64 + lane;                  // 144 descs: 16 local pos x 9 taps
        if (idx < 144) {
            int pl  = idx / 9;                  // local pos
            int tap = idx - pl*9;
            int kh = tap/3, kw = tap - (tap/3)*3;
            int pos = w*16 + pl;
            int r = pos >> 5, c = pos & 31;
            float2 o2 = *(const float2*)(offL + pl*18 + 2*tap);
            float py = (float)(i0 + r - 1 + kh) + o2.x;
            float px = (float)(j0 + c - 1 + kw) + o2.y;
            float y0f = floorf(py), x0f = floorf(px);
            float dy = py - y0f, dx = px - x0f;
            int y0 = (int)y0f, x0i = (int)x0f;
            int y1 = y0 + 1,  x1 = x0i + 1;
            bool vy0 = (y0>=0)&(y0<H_),   vy1 = (y1>=0)&(y1<H_);
            bool vx0 = (x0i>=0)&(x0i<W_), vx1 = (x1>=0)&(x1<W_);
            int yc0 = min(max(y0,0),H_-1),  yc1 = min(max(y1,0),H_-1);
            int xc0 = min(max(x0i,0),W_-1), xc1 = min(max(x1,0),W_-1);
            float w00 = (1.f-dy)*(1.f-dx) * ((vy0&&vx0)?1.f:0.f);
            float w01 = (1.f-dy)*dx       * ((vy0&&vx1)?1.f:0.f);
            float w10 = dy*(1.f-dx)       * ((vy1&&vx0)?1.f:0.f);
            float w11 = dy*dx             * ((vy1&&vx1)?1.f:0.f);
            int hy0 = yc0 - (i0-2), hy1 = yc1 - (i0-2);
            int hx0 = xc0 - (j0-2), hx1 = xc1 - (j0-2);
            bool inh = ((unsigned)hy0 < 6u) & ((unsigned)hy1 < 6u)
                     & ((unsigned)hx0 < 36u) & ((unsigned)hx1 < 36u);
            unsigned a0,a1,a2,a3;
            if (inh) { a0 = hy0*36+hx0; a1 = hy0*36+hx1; a2 = hy1*36+hx0; a3 = hy1*36+hx1; }
            else     { a0 = ((yc0<<7)+xc0) | 0x8000u; a1 = (yc0<<7)+xc1;
                       a2 = (yc1<<7)+xc0;             a3 = (yc1<<7)+xc1; }
            __half2 hw0 = __floats2half2_rn(w00, w01);
            __half2 hw1 = __floats2half2_rn(w10, w11);
            dreg[e].x = a0 | (a1 << 16);
            dreg[e].y = a2 | (a3 << 16);
            dreg[e].z = *(unsigned*)&hw0;
            dreg[e].w = *(unsigned*)&hw1;
        }
    }
    // all offL reads above precede these stores in wave program order -> safe alias
    #pragma unroll
    for (int e = 0; e < 3; ++e) {
        int idx = e*64 + lane;
        if (idx < 144) *(uint4*)(desc + idx*16) = dreg[e];
    }
    // NO barrier: Phase B reads only this wave's desc.

    // ================= Phase B: own-pos sample + MFMA, barrier-free =================
    floatx4 acc[4];
    #pragma unroll
    for (int og = 0; og < 4; ++og) acc[og] = (floatx4){0.f,0.f,0.f,0.f};

    const char* hq0 = halo_c + q*CHS2;
    const char* hq1 = halo_c + (q+4)*CHS2;

    #pragma unroll 3
    for (int tap = 0; tap < 9; ++tap) {
        uint4 d = *(const uint4*)(desc + (m*9 + tap)*16);
        unsigned p0i = d.x & 0x7fffu, p1i = d.x >> 16;
        unsigned p2i = d.y & 0xffffu, p3i = d.y >> 16;
        bool inh = (d.x & 0x8000u) == 0u;
        unsigned short b00 = (unsigned short)(d.z & 0xffffu);
        unsigned short b01 = (unsigned short)(d.z >> 16);
        unsigned short b10 = (unsigned short)(d.w & 0xffffu);
        unsigned short b11 = (unsigned short)(d.w >> 16);
        _Float16 h00 = *(_Float16*)&b00, h01 = *(_Float16*)&b01;
        _Float16 h10 = *(_Float16*)&b10, h11 = *(_Float16*)&b11;
        half8 W00 = {h00,h00,h00,h00,h00,h00,h00,h00};
        half8 W01 = {h01,h01,h01,h01,h01,h01,h01,h01};
        half8 W10 = {h10,h10,h10,h10,h10,h10,h10,h10};
        half8 W11 = {h11,h11,h11,h11,h11,h11,h11,h11};
        half8 v00a,v01a,v10a,v11a, v00b,v01b,v10b,v11b;
        if (inh) {
            v00a = *(const half8*)(hq0 + p0i*16);  v00b = *(const half8*)(hq1 + p0i*16);
            v01a = *(const half8*)(hq0 + p1i*16);  v01b = *(const half8*)(hq1 + p1i*16);
            v10a = *(const half8*)(hq0 + p2i*16);  v10b = *(const half8*)(hq1 + p2i*16);
            v11a = *(const half8*)(hq0 + p3i*16);  v11b = *(const half8*)(hq1 + p3i*16);
        } else {
            // rare out-of-halo: scalar f32 NCHW gathers (exec-masked)
            #pragma unroll
            for (int e = 0; e < 8; ++e) {
                v00a[e] = (_Float16)xf[(q*8+e)*HW_ + (int)p0i];
                v00b[e] = (_Float16)xf[((q+4)*8+e)*HW_ + (int)p0i];
                v01a[e] = (_Float16)xf[(q*8+e)*HW_ + (int)p1i];
                v01b[e] = (_Float16)xf[((q+4)*8+e)*HW_ + (int)p1i];
                v10a[e] = (_Float16)xf[(q*8+e)*HW_ + (int)p2i];
                v10b[e] = (_Float16)xf[((q+4)*8+e)*HW_ + (int)p2i];
                v11a[e] = (_Float16)xf[(q*8+e)*HW_ + (int)p3i];
                v11b[e] = (_Float16)xf[((q+4)*8+e)*HW_ + (int)p3i];
            }
        }
        half8 sk0 = v00a*W00 + v01a*W01 + v10a*W10 + v11a*W11;
        half8 sk1 = v00b*W00 + v01b*W01 + v10b*W10 + v11b*W11;
        #pragma unroll
        for (int og = 0; og < 4; ++og) {
            half8 bf0 = *(const half8*)(W2L + (((tap*2+0)*4+og)<<9) + (lane<<3));
            acc[og] = __builtin_amdgcn_mfma_f32_16x16x32_f16(sk0, bf0, acc[og], 0, 0, 0);
            half8 bf1 = *(const half8*)(W2L + (((tap*2+1)*4+og)<<9) + (lane<<3));
            acc[og] = __builtin_amdgcn_mfma_f32_16x16x32_f16(sk1, bf1, acc[og], 0, 0, 0);
        }
    }
    __syncthreads();   // barrier 2 of 3: halo (cross-wave) dead; E aliases it

    // epilogue: D col=m -> o=og*16+m, row=q*4+r -> pos=w*16+q*4+r
    float* E = (float*)smem;   // [64 pos][66]
    #pragma unroll
    for (int og = 0; og < 4; ++og) {
        #pragma unroll
        for (int r = 0; r < 4; ++r)
            E[(w*16 + q*4 + r)*66 + og*16 + m] = acc[og][r];
    }
    __syncthreads();   // barrier 3 of 3: E reads are cross-wave
    int obase = (b*64)*HW_ + i0*W_ + j0;
    int orow = (lane >> 5)*W_ + (lane & 31);
    #pragma unroll
    for (int rep = 0; rep < 16; ++rep) {
        int o = rep*4 + w;
        out[obase + o*HW_ + orow] = E[lane*66 + o] + b_dcn[o];
    }
}

extern "C" void kernel_launch(void* const* d_in, const int* in_sizes, int n_in,
                              void* d_out, int out_size, void* d_ws, size_t ws_size,
                              hipStream_t stream) {
    const float* x     = (const float*)d_in[0];
    const float* w_off = (const float*)d_in[1];
    const float* b_off = (const float*)d_in[2];
    const float* w_dcn = (const float*)d_in[3];
    const float* b_dcn = (const float*)d_in[4];
    float* out = (float*)d_out;

    __half* W2L = (__half*)d_ws;                    // 73,728 B
    __half* W0L = (__half*)((char*)d_ws + 73728);   // 36,864 B

    k_prep_w<<<216, 256, 0, stream>>>(w_dcn, w_off, W2L, W0L);
    k_fused<<<1024, 256, 0, stream>>>(x, (const _Float16*)W2L,
                                      (const _Float16*)W0L, b_off, b_dcn, out);
}

// Round 11
// 94.473 us; speedup vs baseline: 1.1399x; 1.0231x over previous
//
#include <hip/hip_runtime.h>
#include <hip/hip_fp16.h>

#define B_ 4
#define H_ 128
#define W_ 128
#define HW_ 16384

typedef _Float16 half8 __attribute__((ext_vector_type(8)));
typedef float floatx16 __attribute__((ext_vector_type(16)));

// ws layout (bytes):
//   W2L : f16 [9 tap][4 ks][2 og][64 lane][8] = 73,728  at offset 0   (B-frags, 32x32x16)
//   W0L : f16 [9 tap][4 ks][64 lane][8]       = 36,864  at offset 73,728

// ---------------- prep: weight swizzles for 32x32x16 B-fragments ----------------
// B-frag mapping (mirrors verified 16x16x32 pattern): n = lane&31 (=o/oc),
// k = (lane>>5)*8 + e within a 16-wide k-step.
__global__ __launch_bounds__(256) void k_prep_w(
    const float* __restrict__ w_dcn, const float* __restrict__ w_off,
    __half* __restrict__ W2L, __half* __restrict__ W0L)
{
    int idx = blockIdx.x*256 + threadIdx.x;     // exactly 55,296 threads
    if (idx < 36864) {
        int e = idx & 7, lane = (idx>>3) & 63, og = (idx>>9) & 1;
        int ks = (idx>>10) & 3, tap = idx >> 12;
        int o = og*32 + (lane & 31);
        int c = ks*16 + (lane >> 5)*8 + e;
        W2L[idx] = __float2half(w_dcn[o*576 + c*9 + tap]);
    } else {
        int i2 = idx - 36864;
        int e = i2 & 7, lane = (i2>>3) & 63;
        int ks = (i2>>9) & 3, tap = i2 >> 11;
        int oc = lane & 31;
        int c = ks*16 + (lane >> 5)*8 + e;
        W0L[i2] = (oc < 18) ? __float2half(w_off[oc*576 + c*9 + tap])
                            : __float2half(0.f);
    }
}

// ---------------- fused kernel ----------------
// block = 128 thr = 2 waves; 64-position tile (2 rows x 32 cols). Wave v owns
// row v: 32 positions x ALL 64 o via two 32x32x16 D-tiles -> weight bytes per
// position HALVED vs the 16x16x32 scheme (the R10 TA bottleneck).
// A-frag: m = lane&31 (=pos col), k = (lane>>5)*8+e. C/D: col=lane&31 (=o),
// row = (reg&3)+8*(reg>>2)+4*(lane>>5) (=pos col).
// LDS = 37,120 B -> 4 blocks/CU (8 waves):
//   haloT : [8 chunk][216 pix(6r x 36c)] b128, chunk stride 3488 B
//   wave region[v] (4,608 B): offL[32 pos][18 f32] (2,304 B) then overwritten
//     in-wave by desc[9 tap][32 pos][16 B] (reads reg-staged first; same-wave
//     DS ops are in-order so no barrier needed)
//   epilogue E[64][66] f32 (16,896 B) aliases haloT after final barrier
#define CHS2 3488
#define WLOC_OFF 27904
#define SMEM_SZ 37120

__global__ __launch_bounds__(128, 2) void k_fused(
    const float* __restrict__ x, const _Float16* __restrict__ W2L,
    const _Float16* __restrict__ W0L, const float* __restrict__ b_off,
    const float* __restrict__ b_dcn, float* __restrict__ out)
{
    __shared__ __attribute__((aligned(16))) char smem[SMEM_SZ];
    char* halo_c = smem;

    int t = threadIdx.x;
    int lane = t & 63;
    int v = __builtin_amdgcn_readfirstlane(t >> 6);   // wave id 0/1 = tile row
    int c31 = lane & 31;                              // pos col / o col / oc
    int h8  = lane >> 5;                              // k-octet half

    char*  wl   = smem + WLOC_OFF + v*4608;
    float* offL = (float*)wl;                         // [32 pos][18] f32
    char*  desc = wl;                                 // [9 tap][32 pos][16 B]

    // XCD swizzle: contiguous half-image (one batch half) per XCD
    int bid  = blockIdx.x;
    int xcd  = bid & 7, sidx = bid >> 3;
    int orig = xcd*128 + sidx;
    int b    = orig >> 8;
    int rem  = orig & 255;
    int i0   = (rem >> 2) * 2;     // row-pair base
    int j0   = (rem & 3) * 32;     // col base

    const float* xf = x + (size_t)b * (64*HW_);

    // ---------- stage 6-row x 36-col halo from f32 NCHW, chunk-transposed ----------
    for (int rep = 0; rep < 14; ++rep) {
        int idx = rep*128 + t;                  // 1728 tasks
        if (idx < 1728) {
            int ch = idx / 216, pl = idx - ch*216;
            int hr = pl / 36, hx = pl - hr*36;
            int grow = min(max(i0 - 2 + hr, 0), H_-1);
            int gcol = min(max(j0 - 2 + hx, 0), W_-1);
            int gpix = (grow<<7) + gcol;
            const float* s = xf + ch*8*HW_ + gpix;
            half8 vv;
            #pragma unroll
            for (int e = 0; e < 8; ++e) vv[e] = (_Float16)s[e*HW_];
            *(half8*)(halo_c + ch*CHS2 + pl*16) = vv;
        }
    }
    __syncthreads();   // barrier 1 of 3

    // ================= Phase A: offset conv (one 32x32 D-tile, oc<=18 used) =========
    floatx16 accA = {0.f,0.f,0.f,0.f,0.f,0.f,0.f,0.f,0.f,0.f,0.f,0.f,0.f,0.f,0.f,0.f};
    const half8 hz = {0,0,0,0,0,0,0,0};
    #pragma unroll
    for (int tap = 0; tap < 9; ++tap) {
        int kh = tap/3, kw = tap - (tap/3)*3;
        int ii = i0 + v - 1 + kh;
        int jj = j0 + c31 - 1 + kw;
        bool valid = (ii >= 0) && (ii < H_) && (jj >= 0) && (jj < W_);
        int pixA = (v + 1 + kh)*36 + (c31 + 1 + kw);
        #pragma unroll
        for (int s = 0; s < 4; ++s) {
            half8 a = *(const half8*)(halo_c + (s*2 + h8)*CHS2 + pixA*16);
            a = valid ? a : hz;
            half8 bf = *(const half8*)(W0L + ((tap*4+s)<<9) + (lane<<3));
            accA = __builtin_amdgcn_mfma_f32_32x32x16_f16(a, bf, accA, 0, 0, 0);
        }
    }
    // epilogue A (wave-local): col=c31 (=oc), row=(r&3)+8*(r>>2)+4*h8 (=local pos)
    {
        int oc = c31;
        if (oc < 18) {
            float bo = b_off[oc];
            #pragma unroll
            for (int r = 0; r < 16; ++r) {
                int row = (r & 3) + 8*(r >> 2) + 4*h8;
                offL[row*18 + oc] = accA[r] + bo;
            }
        }
    }
    // NO barrier: offL -> desc -> Phase-B is wave-local (in-order DS ops).

    // ======== descriptor build (wave-local): reads reg-staged, then stores ========
    float2 o2r[5];
    #pragma unroll
    for (int e = 0; e < 5; ++e) {
        int idx = e*64 + lane;                  // 288 descs: 32 pos x 9 taps
        if (idx < 288) {
            int pl = idx / 9, tap = idx - pl*9;
            o2r[e] = *(const float2*)(offL + pl*18 + 2*tap);
        }
    }
    uint4 dreg[5];
    #pragma unroll
    for (int e = 0; e < 5; ++e) {
        int idx = e*64 + lane;
        if (idx < 288) {
            int pl = idx / 9, tap = idx - pl*9;
            int kh = tap/3, kw = tap - (tap/3)*3;
            float py = (float)(i0 + v - 1 + kh) + o2r[e].x;
            float px = (float)(j0 + pl - 1 + kw) + o2r[e].y;
            float y0f = floorf(py), x0f = floorf(px);
            float dy = py - y0f, dx = px - x0f;
            int y0 = (int)y0f, x0i = (int)x0f;
            int y1 = y0 + 1,  x1 = x0i + 1;
            bool vy0 = (y0>=0)&(y0<H_),   vy1 = (y1>=0)&(y1<H_);
            bool vx0 = (x0i>=0)&(x0i<W_), vx1 = (x1>=0)&(x1<W_);
            int yc0 = min(max(y0,0),H_-1),  yc1 = min(max(y1,0),H_-1);
            int xc0 = min(max(x0i,0),W_-1), xc1 = min(max(x1,0),W_-1);
            float w00 = (1.f-dy)*(1.f-dx) * ((vy0&&vx0)?1.f:0.f);
            float w01 = (1.f-dy)*dx       * ((vy0&&vx1)?1.f:0.f);
            float w10 = dy*(1.f-dx)       * ((vy1&&vx0)?1.f:0.f);
            float w11 = dy*dx             * ((vy1&&vx1)?1.f:0.f);
            int hy0 = yc0 - (i0-2), hy1 = yc1 - (i0-2);
            int hx0 = xc0 - (j0-2), hx1 = xc1 - (j0-2);
            bool inh = ((unsigned)hy0 < 6u) & ((unsigned)hy1 < 6u)
                     & ((unsigned)hx0 < 36u) & ((unsigned)hx1 < 36u);
            unsigned a0,a1,a2,a3;
            if (inh) { a0 = hy0*36+hx0; a1 = hy0*36+hx1; a2 = hy1*36+hx0; a3 = hy1*36+hx1; }
            else     { a0 = ((yc0<<7)+xc0) | 0x8000u; a1 = (yc0<<7)+xc1;
                       a2 = (yc1<<7)+xc0;             a3 = (yc1<<7)+xc1; }
            __half2 hw0 = __floats2half2_rn(w00, w01);
            __half2 hw1 = __floats2half2_rn(w10, w11);
            dreg[e].x = a0 | (a1 << 16);
            dreg[e].y = a2 | (a3 << 16);
            dreg[e].z = *(unsigned*)&hw0;
            dreg[e].w = *(unsigned*)&hw1;
        }
    }
    #pragma unroll
    for (int e = 0; e < 5; ++e) {
        int idx = e*64 + lane;
        if (idx < 288) {
            int pl = idx / 9, tap = idx - pl*9;
            *(uint4*)(desc + (tap*32 + pl)*16) = dreg[e];   // [tap][pos] layout
        }
    }
    // NO barrier: Phase B reads only this wave's desc.

    // ================= Phase B: own-pos sample + 32x32x16 MFMA =================
    floatx16 acc0 = {0.f,0.f,0.f,0.f,0.f,0.f,0.f,0.f,0.f,0.f,0.f,0.f,0.f,0.f,0.f,0.f};
    floatx16 acc1 = acc0;

    const char* hqs0 = halo_c + (0*2 + h8)*CHS2;
    const char* hqs1 = halo_c + (1*2 + h8)*CHS2;
    const char* hqs2 = halo_c + (2*2 + h8)*CHS2;
    const char* hqs3 = halo_c + (3*2 + h8)*CHS2;

    #pragma unroll 3
    for (int tap = 0; tap < 9; ++tap) {
        uint4 d = *(const uint4*)(desc + (tap*32 + c31)*16);   // lanes l,l+32 same addr
        unsigned p0i = d.x & 0x7fffu, p1i = d.x >> 16;
        unsigned p2i = d.y & 0xffffu, p3i = d.y >> 16;
        bool inh = (d.x & 0x8000u) == 0u;
        unsigned short b00 = (unsigned short)(d.z & 0xffffu);
        unsigned short b01 = (unsigned short)(d.z >> 16);
        unsigned short b10 = (unsigned short)(d.w & 0xffffu);
        unsigned short b11 = (unsigned short)(d.w >> 16);
        _Float16 h00 = *(_Float16*)&b00, h01 = *(_Float16*)&b01;
        _Float16 h10 = *(_Float16*)&b10, h11 = *(_Float16*)&b11;
        half8 W00 = {h00,h00,h00,h00,h00,h00,h00,h00};
        half8 W01 = {h01,h01,h01,h01,h01,h01,h01,h01};
        half8 W10 = {h10,h10,h10,h10,h10,h10,h10,h10};
        half8 W11 = {h11,h11,h11,h11,h11,h11,h11,h11};
        half8 sk[4];
        const char* hb[4] = {hqs0, hqs1, hqs2, hqs3};
        #pragma unroll
        for (int s = 0; s < 4; ++s) {
            half8 v00, v01, v10, v11;
            if (inh) {
                v00 = *(const half8*)(hb[s] + p0i*16);
                v01 = *(const half8*)(hb[s] + p1i*16);
                v10 = *(const half8*)(hb[s] + p2i*16);
                v11 = *(const half8*)(hb[s] + p3i*16);
            } else {
                int chb = (s*2 + h8)*8;
                #pragma unroll
                for (int e = 0; e < 8; ++e) {
                    v00[e] = (_Float16)xf[(chb+e)*HW_ + (int)p0i];
                    v01[e] = (_Float16)xf[(chb+e)*HW_ + (int)p1i];
                    v10[e] = (_Float16)xf[(chb+e)*HW_ + (int)p2i];
                    v11[e] = (_Float16)xf[(chb+e)*HW_ + (int)p3i];
                }
            }
            sk[s] = v00*W00 + v01*W01 + v10*W10 + v11*W11;
        }
        #pragma unroll
        for (int s = 0; s < 4; ++s) {
            half8 bf0 = *(const half8*)(W2L + (((tap*4+s)*2+0)<<9) + (lane<<3));
            acc0 = __builtin_amdgcn_mfma_f32_32x32x16_f16(sk[s], bf0, acc0, 0, 0, 0);
            half8 bf1 = *(const half8*)(W2L + (((tap*4+s)*2+1)<<9) + (lane<<3));
            acc1 = __builtin_amdgcn_mfma_f32_32x32x16_f16(sk[s], bf1, acc1, 0, 0, 0);
        }
    }
    __syncthreads();   // barrier 2 of 3: halo dead; E aliases it

    // epilogue: E[64 pos][66]; D col=c31 -> o=og*32+c31, row -> pos=v*32+row
    float* E = (float*)smem;
    #pragma unroll
    for (int r = 0; r < 16; ++r) {
        int row = (r & 3) + 8*(r >> 2) + 4*h8;
        int pl  = v*32 + row;
        E[pl*66 + c31]      = acc0[r];
        E[pl*66 + 32 + c31] = acc1[r];
    }
    __syncthreads();   // barrier 3 of 3
    int obase = (b*64)*HW_ + i0*W_ + j0;
    int prow = (lane >> 5)*W_ + c31;
    #pragma unroll
    for (int rep = 0; rep < 32; ++rep) {
        int o = rep*2 + v;
        out[obase + o*HW_ + prow] = E[lane*66 + o] + b_dcn[o];
    }
}

extern "C" void kernel_launch(void* const* d_in, const int* in_sizes, int n_in,
                              void* d_out, int out_size, void* d_ws, size_t ws_size,
                              hipStream_t stream) {
    const float* x     = (const float*)d_in[0];
    const float* w_off = (const float*)d_in[1];
    const float* b_off = (const float*)d_in[2];
    const float* w_dcn = (const float*)d_in[3];
    const float* b_dcn = (const float*)d_in[4];
    float* out = (float*)d_out;

    __half* W2L = (__half*)d_ws;                    // 73,728 B
    __half* W0L = (__half*)((char*)d_ws + 73728);   // 36,864 B

    k_prep_w<<<216, 256, 0, stream>>>(w_dcn, w_off, W2L, W0L);
    k_fused<<<1024, 128, 0, stream>>>(x, (const _Float16*)W2L,
                                      (const _Float16*)W0L, b_off, b_dcn, out);
}